// Round 6
// baseline (353.358 us; speedup 1.0000x reference)
//
#include <hip/hip_runtime.h>
#include <hip/hip_bf16.h>
#include <cstddef>
#include <cstdint>

typedef unsigned short u16;
typedef unsigned int uint32;
typedef __attribute__((ext_vector_type(8))) short bf16x8;
typedef __attribute__((ext_vector_type(4))) float f32x4;

#define SPATIAL 16384
#define TOTAL_M 131072

__device__ __forceinline__ u16 f2b(float f) {
  __hip_bfloat16 h = __float2bfloat16(f);
  return *reinterpret_cast<u16*>(&h);
}
__device__ __forceinline__ uint32 pk2(float a, float b) {
  return (uint32)f2b(a) | ((uint32)f2b(b) << 16);
}
__device__ __forceinline__ float blo(uint32 u) {
  union { uint32 u; float f; } c; c.u = u << 16; return c.f;
}
__device__ __forceinline__ float bhi(uint32 u) {
  union { uint32 u; float f; } c; c.u = u & 0xffff0000u; return c.f;
}

// async global->LDS, 16B per lane; lds base must be wave-uniform
__device__ __forceinline__ void gload_lds16(const u16* g, u16* l) {
  __builtin_amdgcn_global_load_lds(
      (const __attribute__((address_space(1))) void*)g,
      (__attribute__((address_space(3))) void*)l, 16, 0, 0);
}

// token base (element index into [131072][768]) for window gw, in-window token tt
template <int WS>
__device__ __forceinline__ size_t tok_base(int gw, int tt) {
  constexpr int WG = 128 / WS;
  constexpr int NWIN = WG * WG;
  int bb = gw / NWIN, rr = gw % NWIN;
  int gy = rr / WG, gx = rr % WG;
  int yy = gy * WS + tt / WS, xx = gx * WS + tt % WS;
  return (((size_t)bb * 128 + yy) * 128 + xx) * 768;
}

// ---------------- Kernel 0: prep -----------------------------------------
// blocks 0..2047: transpose+convert x [b][k][sp] fp32 -> xT [m][k] bf16
// blocks 2048..2063: convert qkv_w / proj_w fp32 -> bf16
__global__ __launch_bounds__(256) void prep(const float* __restrict__ x,
                                            const float* __restrict__ qw,
                                            const float* __restrict__ pw,
                                            u16* __restrict__ xT,
                                            u16* __restrict__ wq,
                                            u16* __restrict__ wp) {
  const int tid = threadIdx.x;
  const int bid = blockIdx.x;
  if (bid >= 2048) {
    const int t = (bid - 2048) * 256 + tid;
#pragma unroll
    for (int i = 0; i < 16; ++i) {
      const int e = i * 4096 + t;  // float4 index, 65536 total
      if (e < 49152) {
        float4 v = *(const float4*)&qw[(size_t)e * 4];
        ushort4 o;
        o.x = f2b(v.x); o.y = f2b(v.y); o.z = f2b(v.z); o.w = f2b(v.w);
        *(ushort4*)&wq[(size_t)e * 4] = o;
      } else {
        float4 v = *(const float4*)&pw[(size_t)(e - 49152) * 4];
        ushort4 o;
        o.x = f2b(v.x); o.y = f2b(v.y); o.z = f2b(v.z); o.w = f2b(v.w);
        *(ushort4*)&wp[(size_t)(e - 49152) * 4] = o;
      }
    }
    return;
  }
  __shared__ u16 Ts[64 * 256];
  const int b = bid >> 8;
  const int sp0 = (bid & 255) * 64;
#pragma unroll
  for (int it = 0; it < 16; ++it) {
    int e = it * 256 + tid;
    int k = e >> 4;
    int c4 = (e & 15) * 4;
    float4 v = *(const float4*)&x[(((size_t)(b * 256 + k)) << 14) + sp0 + c4];
    Ts[(c4 + 0) * 256 + (k ^ ((((c4 + 0)) & 31) << 3))] = f2b(v.x);
    Ts[(c4 + 1) * 256 + (k ^ ((((c4 + 1)) & 31) << 3))] = f2b(v.y);
    Ts[(c4 + 2) * 256 + (k ^ ((((c4 + 2)) & 31) << 3))] = f2b(v.z);
    Ts[(c4 + 3) * 256 + (k ^ ((((c4 + 3)) & 31) << 3))] = f2b(v.w);
  }
  __syncthreads();
#pragma unroll
  for (int it = 0; it < 8; ++it) {
    int e = it * 256 + tid;
    int sp = e >> 5;
    int kc = (e & 31) * 8;
    bf16x8 row = *(const bf16x8*)&Ts[sp * 256 + (kc ^ ((sp & 31) << 3))];
    *(bf16x8*)&xT[((size_t)(b * 16384 + sp0 + sp)) * 256 + kc] = row;
  }
}

// ---------------- Kernel 1: qkv GEMM — A-panel-once, barrier-free loop ---
// A = xT [131072][256] bf16, B = wq [768][256] bf16, C = qkv bf16.
// M-tile 64: A panel (64x256 = 32KB) staged to LDS ONCE (XOR-swizzled via
// pre-swizzled global source). B fragments load global->reg (wq is 384KB,
// L2-resident, reused by every block). No barriers in the n/k loops: waves
// drift freely, stores overlap next tile's compute. ~5 blocks/CU.
__global__ __launch_bounds__(256) void gemm_qkv(const u16* __restrict__ xT,
                                                const u16* __restrict__ wq,
                                                u16* __restrict__ qkv) {
  __shared__ u16 As[64 * 256];
  const int tid = threadIdx.x;
  const int m0 = blockIdx.x * 64;
  const int lane = tid & 63, w = tid >> 6;
  const int fr = lane & 15, fk = lane >> 4;
  const int frx = (fr & 7) << 3;

  // stage A once: 64 rows x 32 chunks of 16B; linear LDS dest,
  // inverse-swizzled global source (chunk c -> c ^ (row&7))
#pragma unroll
  for (int it = 0; it < 8; ++it) {
    int e = it * 256 + tid;
    int row = e >> 5, c = e & 31;
    u16* la = &As[(it * 256 + (tid & 192)) * 8];
    gload_lds16(&xT[((size_t)(m0 + row) << 8) + ((c * 8) ^ ((row & 7) << 3))], la);
  }
  asm volatile("s_waitcnt vmcnt(0)" ::: "memory");
  __syncthreads();

  for (int nt = 0; nt < 6; ++nt) {
    const int nb = nt * 128 + w * 32;  // wave owns a 32-col slice
    f32x4 acc[4][2] = {};
#pragma unroll
    for (int ks = 0; ks < 8; ++ks) {
      const int kb = ks * 32 + fk * 8;
      bf16x8 bfr[2];
#pragma unroll
      for (int j = 0; j < 2; ++j)
        bfr[j] = *(const bf16x8*)&wq[((size_t)(nb + j * 16 + fr) << 8) + kb];
      bf16x8 af[4];
#pragma unroll
      for (int i = 0; i < 4; ++i)
        af[i] = *(const bf16x8*)&As[(i * 16 + fr) * 256 + (kb ^ frx)];
#pragma unroll
      for (int i = 0; i < 4; ++i)
#pragma unroll
        for (int j = 0; j < 2; ++j)
          acc[i][j] = __builtin_amdgcn_mfma_f32_16x16x32_bf16(bfr[j], af[i], acc[i][j], 0, 0, 0);
    }
    // acc[i][j][r] = C[m0 + i*16 + fr][nb + j*16 + fk*4 + r]
#pragma unroll
    for (int i = 0; i < 4; ++i) {
      const size_t row = (size_t)(m0 + i * 16 + fr) * 768;
#pragma unroll
      for (int j = 0; j < 2; ++j) {
        uint2 p;
        p.x = pk2(acc[i][j][0], acc[i][j][1]);
        p.y = pk2(acc[i][j][2], acc[i][j][3]);
        *(uint2*)&qkv[row + nb + j * 16 + fk * 4] = p;
      }
    }
  }
}

// ---------------- Kernel 2a: small-window attention body (fp32 VALU) -----
template <int WS>
__device__ __forceinline__ void win_attn_body(u16* __restrict__ qkv, int head,
                                              int bid, u16 (*Ks)[68], u16 (*Vs)[68]) {
  constexpr int T = WS * WS;
  constexpr int G = 256 / T;
  const int tid = threadIdx.x;
  const int gw0 = bid * G;
  const int qoff = head * 64;

#pragma unroll
  for (int i = 0; i < 16; ++i) {
    int e4 = i * 256 + tid;
    int tok = e4 >> 4;
    int d4 = (e4 & 15) * 4;
    size_t base = tok_base<WS>(gw0 + tok / T, tok % T);
    *(uint2*)&Ks[tok][d4] = *(const uint2*)&qkv[base + 256 + qoff + d4];
    *(uint2*)&Vs[tok][d4] = *(const uint2*)&qkv[base + 512 + qoff + d4];
  }
  __syncthreads();

  const int myw = tid / T;
  const int mytt = tid % T;
  const size_t mybase = tok_base<WS>(gw0 + myw, mytt);

  float q[64];
#pragma unroll
  for (int d4 = 0; d4 < 16; ++d4) {
    uint2 q2 = *(const uint2*)&qkv[mybase + qoff + d4 * 4];
    q[d4 * 4 + 0] = blo(q2.x); q[d4 * 4 + 1] = bhi(q2.x);
    q[d4 * 4 + 2] = blo(q2.y); q[d4 * 4 + 3] = bhi(q2.y);
  }
  const int rbase = myw * T;

  float mmax = -1e30f, lsum = 0.f;
  for (int j = 0; j < T; ++j) {
    float s = 0.f;
#pragma unroll
    for (int d4 = 0; d4 < 16; ++d4) {
      uint2 k2 = *(const uint2*)&Ks[rbase + j][d4 * 4];
      s = fmaf(q[d4 * 4 + 0], blo(k2.x), s);
      s = fmaf(q[d4 * 4 + 1], bhi(k2.x), s);
      s = fmaf(q[d4 * 4 + 2], blo(k2.y), s);
      s = fmaf(q[d4 * 4 + 3], bhi(k2.y), s);
    }
    s *= 0.125f;
    const float mn = fmaxf(mmax, s);
    lsum = lsum * __expf(mmax - mn) + __expf(s - mn);
    mmax = mn;
  }
  const float inv = 1.f / lsum;

  float acc[64] = {};
  for (int j = 0; j < T; ++j) {
    float s = 0.f;
#pragma unroll
    for (int d4 = 0; d4 < 16; ++d4) {
      uint2 k2 = *(const uint2*)&Ks[rbase + j][d4 * 4];
      s = fmaf(q[d4 * 4 + 0], blo(k2.x), s);
      s = fmaf(q[d4 * 4 + 1], bhi(k2.x), s);
      s = fmaf(q[d4 * 4 + 2], blo(k2.y), s);
      s = fmaf(q[d4 * 4 + 3], bhi(k2.y), s);
    }
    const float p = __expf(s * 0.125f - mmax) * inv;
#pragma unroll
    for (int d4 = 0; d4 < 16; ++d4) {
      uint2 v2 = *(const uint2*)&Vs[rbase + j][d4 * 4];
      acc[d4 * 4 + 0] = fmaf(p, blo(v2.x), acc[d4 * 4 + 0]);
      acc[d4 * 4 + 1] = fmaf(p, bhi(v2.x), acc[d4 * 4 + 1]);
      acc[d4 * 4 + 2] = fmaf(p, blo(v2.y), acc[d4 * 4 + 2]);
      acc[d4 * 4 + 3] = fmaf(p, bhi(v2.y), acc[d4 * 4 + 3]);
    }
  }
#pragma unroll
  for (int d4 = 0; d4 < 16; ++d4) {
    uint2 o2;
    o2.x = pk2(acc[d4 * 4 + 0], acc[d4 * 4 + 1]);
    o2.y = pk2(acc[d4 * 4 + 2], acc[d4 * 4 + 3]);
    *(uint2*)&qkv[mybase + qoff + d4 * 4] = o2;
  }
}

// merged heads 0 (ws=2) and 1 (ws=4): one launch, latency overlaps
__global__ __launch_bounds__(256) void win_small(u16* __restrict__ qkv) {
  __shared__ u16 Ks[256][68];
  __shared__ u16 Vs[256][68];
  if (blockIdx.x < 512)
    win_attn_body<2>(qkv, 0, blockIdx.x, Ks, Vs);
  else
    win_attn_body<4>(qkv, 1, blockIdx.x - 512, Ks, Vs);
}

// ---------------- Kernel 2b: MFMA windowed attention (ws=8/16) ----------
template <int WS>
__global__ __launch_bounds__(256) void win_attn_mfma(u16* __restrict__ qkv, int head) {
  constexpr int T = WS * WS;          // 64 or 256
  constexpr int G = 256 / T;          // windows per block
  constexpr int KT = T / 16;          // 16-key tiles per window
  constexpr int KS = T / 32;          // PV K=32 steps
  constexpr int PL = T + 8;           // padded P row (u16)
  __shared__ u16 Ks[256 * 72];        // [block token][d], pad 72
  __shared__ u16 Vt[64 * 264];        // [d][block token], pad 264
  __shared__ u16 Plds[4 * 16 * PL];   // per-wave [query16][key T]
  const int tid = threadIdx.x;
  const int gw0 = blockIdx.x * G;
  const int qoff = head * 64;

  // stage K (bf16 rows, straight copy) and V (bf16 transposed)
#pragma unroll
  for (int it = 0; it < 16; ++it) {
    int e = it * 256 + tid;
    int tok = e >> 4;
    int d4 = (e & 15) * 4;
    int win = tok / T, tt = tok % T;
    size_t base = tok_base<WS>(gw0 + win, tt);
    uint2 kk = *(const uint2*)&qkv[base + 256 + qoff + d4];
    uint2 vv = *(const uint2*)&qkv[base + 512 + qoff + d4];
    *(uint2*)&Ks[tok * 72 + d4] = kk;
    Vt[(d4 + 0) * 264 + tok] = (u16)(vv.x & 0xffffu);
    Vt[(d4 + 1) * 264 + tok] = (u16)(vv.x >> 16);
    Vt[(d4 + 2) * 264 + tok] = (u16)(vv.y & 0xffffu);
    Vt[(d4 + 3) * 264 + tok] = (u16)(vv.y >> 16);
  }
  __syncthreads();

  const int w = tid >> 6, lane = tid & 63;
  const int fr = lane & 15, fk = lane >> 4;
  u16* prow = &Plds[(w * 16 + fr) * PL];

  for (int qi = 0; qi < 4; ++qi) {
    const int qg = w * 4 + qi;          // global q-tile 0..15
    const int win = qg / (T / 16);
    const int qt = qg % (T / 16);
    const int gw = gw0 + win;

    // Q fragments straight from global bf16
    const size_t qb = tok_base<WS>(gw, qt * 16 + fr) + qoff;
    bf16x8 qf[2];
#pragma unroll
    for (int ds = 0; ds < 2; ++ds)
      qf[ds] = *(const bf16x8*)&qkv[qb + ds * 32 + fk * 8];

    // S^T tiles
    f32x4 sv[KT];
#pragma unroll
    for (int kt = 0; kt < KT; ++kt) {
      const u16* krow = &Ks[(win * T + kt * 16 + fr) * 72];
      bf16x8 k0 = *(const bf16x8*)&krow[fk * 8];
      bf16x8 k1 = *(const bf16x8*)&krow[32 + fk * 8];
      f32x4 s = {};
      s = __builtin_amdgcn_mfma_f32_16x16x32_bf16(k0, qf[0], s, 0, 0, 0);
      s = __builtin_amdgcn_mfma_f32_16x16x32_bf16(k1, qf[1], s, 0, 0, 0);
      sv[kt] = s;
    }

    // softmax for query fr (keys spread over kt,r and the 4 fk-groups)
    float rmax = -3e38f;
#pragma unroll
    for (int kt = 0; kt < KT; ++kt)
#pragma unroll
      for (int r = 0; r < 4; ++r) rmax = fmaxf(rmax, sv[kt][r]);
    rmax = fmaxf(rmax, __shfl_xor(rmax, 16));
    rmax = fmaxf(rmax, __shfl_xor(rmax, 32));
    const float m = rmax * 0.125f;
    float l = 0.f;
#pragma unroll
    for (int kt = 0; kt < KT; ++kt)
#pragma unroll
      for (int r = 0; r < 4; ++r) {
        float ev = __expf(sv[kt][r] * 0.125f - m);
        sv[kt][r] = ev;
        l += ev;
      }
    l += __shfl_xor(l, 16);
    l += __shfl_xor(l, 32);
    const float linv = 1.f / l;

    // P -> LDS [query][key] bf16 (keys fk*4..fk*4+3 contiguous per kt)
#pragma unroll
    for (int kt = 0; kt < KT; ++kt) {
      uint2 pp;
      pp.x = pk2(sv[kt][0], sv[kt][1]);
      pp.y = pk2(sv[kt][2], sv[kt][3]);
      *(uint2*)&prow[kt * 16 + fk * 4] = pp;
    }
    __asm__ __volatile__("s_waitcnt lgkmcnt(0)" ::: "memory");
    __builtin_amdgcn_sched_barrier(0);

    // O = P . V
    f32x4 ov[4] = {};
#pragma unroll
    for (int ks = 0; ks < KS; ++ks) {
      bf16x8 pf = *(const bf16x8*)&prow[ks * 32 + fk * 8];
#pragma unroll
      for (int dt = 0; dt < 4; ++dt) {
        bf16x8 vf = *(const bf16x8*)&Vt[(dt * 16 + fr) * 264 + win * T + ks * 32 + fk * 8];
        ov[dt] = __builtin_amdgcn_mfma_f32_16x16x32_bf16(pf, vf, ov[dt], 0, 0, 0);
      }
    }

    // scale by 1/l (routed from fr-space to fk*4+r-space) and store bf16
#pragma unroll
    for (int r = 0; r < 4; ++r) {
      float lr = __shfl(linv, fk * 4 + r);
      size_t ob = tok_base<WS>(gw, qt * 16 + fk * 4 + r) + qoff;
#pragma unroll
      for (int dt = 0; dt < 4; ++dt)
        qkv[ob + dt * 16 + fr] = f2b(ov[dt][r] * lr);
    }
  }
}

// ---------------- Kernel 3: proj GEMM — A-panel-once, barrier-free loop --
// A = qkv[:,0:256] bf16 (row stride 768), B = wp [256][256] bf16 (L2-hot).
// M-tile 64, A staged once (32KB). Non-swapped mfma so m lands in the
// register direction for coalesced float4 stores to [c][sp] layout.
// Epilogue: + bias + residual.
__global__ __launch_bounds__(256) void gemm_proj(const u16* __restrict__ qkv,
                                                 const u16* __restrict__ wp,
                                                 const float* __restrict__ bias,
                                                 const float* __restrict__ x,
                                                 float* __restrict__ out) {
  __shared__ u16 As[64 * 256];
  const int tid = threadIdx.x;
  const int m0 = blockIdx.x * 64;
  const int lane = tid & 63, w = tid >> 6;
  const int fr = lane & 15, fk = lane >> 4;
  const int frx = (fr & 7) << 3;
  const int b = m0 >> 14;

#pragma unroll
  for (int it = 0; it < 8; ++it) {
    int e = it * 256 + tid;
    int row = e >> 5, c = e & 31;
    u16* la = &As[(it * 256 + (tid & 192)) * 8];
    gload_lds16(&qkv[(size_t)(m0 + row) * 768 + ((c * 8) ^ ((row & 7) << 3))], la);
  }
  asm volatile("s_waitcnt vmcnt(0)" ::: "memory");
  __syncthreads();

  for (int nt = 0; nt < 2; ++nt) {
    const int nb = nt * 128 + w * 32;
    f32x4 acc[4][2] = {};
#pragma unroll
    for (int ks = 0; ks < 8; ++ks) {
      const int kb = ks * 32 + fk * 8;
      bf16x8 bfr[2];
#pragma unroll
      for (int j = 0; j < 2; ++j)
        bfr[j] = *(const bf16x8*)&wp[((size_t)(nb + j * 16 + fr) << 8) + kb];
      bf16x8 af[4];
#pragma unroll
      for (int i = 0; i < 4; ++i)
        af[i] = *(const bf16x8*)&As[(i * 16 + fr) * 256 + (kb ^ frx)];
#pragma unroll
      for (int i = 0; i < 4; ++i)
#pragma unroll
        for (int j = 0; j < 2; ++j)
          acc[i][j] = __builtin_amdgcn_mfma_f32_16x16x32_bf16(af[i], bfr[j], acc[i][j], 0, 0, 0);
    }
    // acc[i][j][r]: m = m0 + i*16 + fk*4 + r, n = nb + j*16 + fr
#pragma unroll
    for (int i = 0; i < 4; ++i) {
      const int sp = (m0 & 16383) + i * 16 + fk * 4;
#pragma unroll
      for (int j = 0; j < 2; ++j) {
        const int n = nb + j * 16 + fr;
        const size_t o = ((size_t)(b * 256 + n) << 14) + sp;
        const float4 r4 = *(const float4*)&x[o];
        const float bb = bias[n];
        float4 v = make_float4(acc[i][j][0] + bb + r4.x, acc[i][j][1] + bb + r4.y,
                               acc[i][j][2] + bb + r4.z, acc[i][j][3] + bb + r4.w);
        *(float4*)&out[o] = v;
      }
    }
  }
}

extern "C" void kernel_launch(void* const* d_in, const int* in_sizes, int n_in,
                              void* d_out, int out_size, void* d_ws, size_t ws_size,
                              hipStream_t stream) {
  const float* x = (const float*)d_in[0];
  const float* qkv_w = (const float*)d_in[1];
  const float* proj_w = (const float*)d_in[2];
  const float* proj_b = (const float*)d_in[3];
  float* out = (float*)d_out;
  // workspace layout (bf16):
  //   qkv : 131072*768 u16 = 192 MiB
  //   xT  : 131072*256 u16 =  64 MiB
  //   wq  : 768*256 u16, wp : 256*256 u16
  u16* qkv = (u16*)d_ws;
  u16* xT = qkv + (size_t)131072 * 768;
  u16* wq = xT + (size_t)131072 * 256;
  u16* wp = wq + (size_t)768 * 256;

  prep<<<2064, 256, 0, stream>>>(x, qkv_w, proj_w, xT, wq, wp);
  gemm_qkv<<<2048, 256, 0, stream>>>(xT, wq, qkv);
  win_small<<<1024, 256, 0, stream>>>(qkv);           // heads 0 (ws2) + 1 (ws4)
  win_attn_mfma<8><<<512, 256, 0, stream>>>(qkv, 2);
  win_attn_mfma<16><<<512, 256, 0, stream>>>(qkv, 3);
  gemm_proj<<<2048, 256, 0, stream>>>(qkv, wp, proj_b, x, out);
}

// Round 7
// 352.225 us; speedup vs baseline: 1.0032x; 1.0032x over previous
//
#include <hip/hip_runtime.h>
#include <hip/hip_bf16.h>
#include <cstddef>
#include <cstdint>

typedef unsigned short u16;
typedef unsigned int uint32;
typedef __attribute__((ext_vector_type(8))) short bf16x8;
typedef __attribute__((ext_vector_type(4))) float f32x4;

#define SPATIAL 16384
#define TOTAL_M 131072

__device__ __forceinline__ u16 f2b(float f) {
  __hip_bfloat16 h = __float2bfloat16(f);
  return *reinterpret_cast<u16*>(&h);
}
__device__ __forceinline__ uint32 pk2(float a, float b) {
  return (uint32)f2b(a) | ((uint32)f2b(b) << 16);
}
__device__ __forceinline__ float blo(uint32 u) {
  union { uint32 u; float f; } c; c.u = u << 16; return c.f;
}
__device__ __forceinline__ float bhi(uint32 u) {
  union { uint32 u; float f; } c; c.u = u & 0xffff0000u; return c.f;
}

// async global->LDS, 16B per lane; lds base must be wave-uniform
__device__ __forceinline__ void gload_lds16(const u16* g, u16* l) {
  __builtin_amdgcn_global_load_lds(
      (const __attribute__((address_space(1))) void*)g,
      (__attribute__((address_space(3))) void*)l, 16, 0, 0);
}

// token base (element index into [131072][768]) for window gw, in-window token tt
template <int WS>
__device__ __forceinline__ size_t tok_base(int gw, int tt) {
  constexpr int WG = 128 / WS;
  constexpr int NWIN = WG * WG;
  int bb = gw / NWIN, rr = gw % NWIN;
  int gy = rr / WG, gx = rr % WG;
  int yy = gy * WS + tt / WS, xx = gx * WS + tt % WS;
  return (((size_t)bb * 128 + yy) * 128 + xx) * 768;
}

// ---------------- Kernel 0: wprep — convert qkv_w / proj_w fp32 -> bf16 --
__global__ __launch_bounds__(256) void wprep(const float* __restrict__ qw,
                                             const float* __restrict__ pw,
                                             u16* __restrict__ wq,
                                             u16* __restrict__ wp) {
  const int t = blockIdx.x * 256 + threadIdx.x;
#pragma unroll
  for (int i = 0; i < 16; ++i) {
    const int e = i * 4096 + t;  // float4 index, 65536 total
    if (e < 49152) {
      float4 v = *(const float4*)&qw[(size_t)e * 4];
      ushort4 o;
      o.x = f2b(v.x); o.y = f2b(v.y); o.z = f2b(v.z); o.w = f2b(v.w);
      *(ushort4*)&wq[(size_t)e * 4] = o;
    } else {
      float4 v = *(const float4*)&pw[(size_t)(e - 49152) * 4];
      ushort4 o;
      o.x = f2b(v.x); o.y = f2b(v.y); o.z = f2b(v.z); o.w = f2b(v.w);
      *(ushort4*)&wp[(size_t)(e - 49152) * 4] = o;
    }
  }
}

// ---------------- Kernel 1: qkv GEMM — fused x-transpose staging ---------
// A read DIRECTLY from x [b][k][sp] fp32 (no prep pass / no xT buffer):
// per K-step each thread loads 8 float4 (k-rows x 4 sp, coalesced 512B),
// transposes 4sp x 8k in registers, cvt_pk to bf16, one ds_write_b128 per
// sp with chunk XOR-swizzle c = kq ^ (sp&7) matching the kb^frx read.
// B staged via async global_load_lds (DMA overlaps A's VALU work).
// XCD-chunked swizzle: 6 n-tiles of an m-tile on one XCD (A L2-hit).
__global__ __launch_bounds__(256) void gemm_qkv(const float* __restrict__ x,
                                                const u16* __restrict__ wq,
                                                u16* __restrict__ qkv) {
  __shared__ u16 As[128 * 64];
  __shared__ u16 Bs[128 * 64];
  const int tid = threadIdx.x;
  const int bid = blockIdx.x;
  const int logical = (bid & 7) * 768 + (bid >> 3);
  const int m0 = (logical / 6) * 128;
  const int n0 = (logical % 6) * 128;
  const int b = m0 >> 14;
  const int sp0 = m0 & 16383;
  const int lane = tid & 63, w = tid >> 6;
  const int wr = w >> 1, wc = w & 1;
  const int fr = lane & 15, fk = lane >> 4;
  const int frx = (fr & 7) << 3;
  const int kcs = ((tid & 7) * 8) ^ (((tid >> 3) & 7) << 3);
  const int srow = tid >> 3;
  const int spq = tid & 31;   // sp quad (4 sp values)
  const int kq8 = tid >> 5;   // k-chunk 0..7 (8 k values)
  f32x4 acc[4][4] = {};
  for (int kt = 0; kt < 4; ++kt) {
    const int k0 = kt * 64;
    // B: async DMA global->LDS (source pre-swizzled, LDS linear)
#pragma unroll
    for (int it = 0; it < 4; ++it) {
      int row = it * 32 + srow;
      u16* lb = &Bs[(it * 256 + (tid & 192)) * 8];
      gload_lds16(&wq[((size_t)(n0 + row) << 8) + k0 + kcs], lb);
    }
    // A: fused transpose-convert from x (fp32)
    float4 xa[8];
#pragma unroll
    for (int j = 0; j < 8; ++j)
      xa[j] = *(const float4*)&x[(((size_t)(b * 256 + k0 + kq8 * 8 + j)) << 14) + sp0 + spq * 4];
#pragma unroll
    for (int s = 0; s < 4; ++s) {
      const int sp = spq * 4 + s;
      union { bf16x8 v; uint32 u[4]; } U;
      U.u[0] = pk2(((const float*)&xa[0])[s], ((const float*)&xa[1])[s]);
      U.u[1] = pk2(((const float*)&xa[2])[s], ((const float*)&xa[3])[s]);
      U.u[2] = pk2(((const float*)&xa[4])[s], ((const float*)&xa[5])[s]);
      U.u[3] = pk2(((const float*)&xa[6])[s], ((const float*)&xa[7])[s]);
      const int ch = kq8 ^ (sp & 7);
      *(bf16x8*)&As[sp * 64 + ch * 8] = U.v;
    }
    __syncthreads();
#pragma unroll
    for (int kk = 0; kk < 2; ++kk) {
      const int kb = (kk * 32 + fk * 8) ^ frx;
      bf16x8 af[4], bfr[4];
#pragma unroll
      for (int i = 0; i < 4; ++i) {
        af[i] = *(const bf16x8*)&As[(wr * 64 + i * 16 + fr) * 64 + kb];
        bfr[i] = *(const bf16x8*)&Bs[(wc * 64 + i * 16 + fr) * 64 + kb];
      }
#pragma unroll
      for (int i = 0; i < 4; ++i)
#pragma unroll
        for (int j = 0; j < 4; ++j)
          acc[i][j] = __builtin_amdgcn_mfma_f32_16x16x32_bf16(bfr[j], af[i], acc[i][j], 0, 0, 0);
    }
    __syncthreads();
  }
  // acc[i][j][r] = C[m = m0+wr*64+i*16+fr][n = n0+wc*64+j*16+fk*4+r]
#pragma unroll
  for (int i = 0; i < 4; ++i) {
    const size_t row = (size_t)(m0 + wr * 64 + i * 16 + fr) * 768;
#pragma unroll
    for (int j = 0; j < 4; ++j) {
      uint2 p;
      p.x = pk2(acc[i][j][0], acc[i][j][1]);
      p.y = pk2(acc[i][j][2], acc[i][j][3]);
      *(uint2*)&qkv[row + n0 + wc * 64 + j * 16 + fk * 4] = p;
    }
  }
}

// ---------------- Kernel 2a: small-window attention body (fp32 VALU) -----
template <int WS>
__device__ __forceinline__ void win_attn_body(u16* __restrict__ qkv, int head,
                                              int bid, u16 (*Ks)[68], u16 (*Vs)[68]) {
  constexpr int T = WS * WS;
  constexpr int G = 256 / T;
  const int tid = threadIdx.x;
  const int gw0 = bid * G;
  const int qoff = head * 64;

#pragma unroll
  for (int i = 0; i < 16; ++i) {
    int e4 = i * 256 + tid;
    int tok = e4 >> 4;
    int d4 = (e4 & 15) * 4;
    size_t base = tok_base<WS>(gw0 + tok / T, tok % T);
    *(uint2*)&Ks[tok][d4] = *(const uint2*)&qkv[base + 256 + qoff + d4];
    *(uint2*)&Vs[tok][d4] = *(const uint2*)&qkv[base + 512 + qoff + d4];
  }
  __syncthreads();

  const int myw = tid / T;
  const int mytt = tid % T;
  const size_t mybase = tok_base<WS>(gw0 + myw, mytt);

  float q[64];
#pragma unroll
  for (int d4 = 0; d4 < 16; ++d4) {
    uint2 q2 = *(const uint2*)&qkv[mybase + qoff + d4 * 4];
    q[d4 * 4 + 0] = blo(q2.x); q[d4 * 4 + 1] = bhi(q2.x);
    q[d4 * 4 + 2] = blo(q2.y); q[d4 * 4 + 3] = bhi(q2.y);
  }
  const int rbase = myw * T;

  float mmax = -1e30f, lsum = 0.f;
  for (int j = 0; j < T; ++j) {
    float s = 0.f;
#pragma unroll
    for (int d4 = 0; d4 < 16; ++d4) {
      uint2 k2 = *(const uint2*)&Ks[rbase + j][d4 * 4];
      s = fmaf(q[d4 * 4 + 0], blo(k2.x), s);
      s = fmaf(q[d4 * 4 + 1], bhi(k2.x), s);
      s = fmaf(q[d4 * 4 + 2], blo(k2.y), s);
      s = fmaf(q[d4 * 4 + 3], bhi(k2.y), s);
    }
    s *= 0.125f;
    const float mn = fmaxf(mmax, s);
    lsum = lsum * __expf(mmax - mn) + __expf(s - mn);
    mmax = mn;
  }
  const float inv = 1.f / lsum;

  float acc[64] = {};
  for (int j = 0; j < T; ++j) {
    float s = 0.f;
#pragma unroll
    for (int d4 = 0; d4 < 16; ++d4) {
      uint2 k2 = *(const uint2*)&Ks[rbase + j][d4 * 4];
      s = fmaf(q[d4 * 4 + 0], blo(k2.x), s);
      s = fmaf(q[d4 * 4 + 1], bhi(k2.x), s);
      s = fmaf(q[d4 * 4 + 2], blo(k2.y), s);
      s = fmaf(q[d4 * 4 + 3], bhi(k2.y), s);
    }
    const float p = __expf(s * 0.125f - mmax) * inv;
#pragma unroll
    for (int d4 = 0; d4 < 16; ++d4) {
      uint2 v2 = *(const uint2*)&Vs[rbase + j][d4 * 4];
      acc[d4 * 4 + 0] = fmaf(p, blo(v2.x), acc[d4 * 4 + 0]);
      acc[d4 * 4 + 1] = fmaf(p, bhi(v2.x), acc[d4 * 4 + 1]);
      acc[d4 * 4 + 2] = fmaf(p, blo(v2.y), acc[d4 * 4 + 2]);
      acc[d4 * 4 + 3] = fmaf(p, bhi(v2.y), acc[d4 * 4 + 3]);
    }
  }
#pragma unroll
  for (int d4 = 0; d4 < 16; ++d4) {
    uint2 o2;
    o2.x = pk2(acc[d4 * 4 + 0], acc[d4 * 4 + 1]);
    o2.y = pk2(acc[d4 * 4 + 2], acc[d4 * 4 + 3]);
    *(uint2*)&qkv[mybase + qoff + d4 * 4] = o2;
  }
}

// merged heads 0 (ws=2) and 1 (ws=4): one launch, latency overlaps
__global__ __launch_bounds__(256) void win_small(u16* __restrict__ qkv) {
  __shared__ u16 Ks[256][68];
  __shared__ u16 Vs[256][68];
  if (blockIdx.x < 512)
    win_attn_body<2>(qkv, 0, blockIdx.x, Ks, Vs);
  else
    win_attn_body<4>(qkv, 1, blockIdx.x - 512, Ks, Vs);
}

// ---------------- Kernel 2b: MFMA windowed attention (ws=8/16) ----------
template <int WS>
__global__ __launch_bounds__(256) void win_attn_mfma(u16* __restrict__ qkv, int head) {
  constexpr int T = WS * WS;          // 64 or 256
  constexpr int G = 256 / T;          // windows per block
  constexpr int KT = T / 16;          // 16-key tiles per window
  constexpr int KS = T / 32;          // PV K=32 steps
  constexpr int PL = T + 8;           // padded P row (u16)
  __shared__ u16 Ks[256 * 72];        // [block token][d], pad 72
  __shared__ u16 Vt[64 * 264];        // [d][block token], pad 264
  __shared__ u16 Plds[4 * 16 * PL];   // per-wave [query16][key T]
  const int tid = threadIdx.x;
  const int gw0 = blockIdx.x * G;
  const int qoff = head * 64;

  // stage K (bf16 rows, straight copy) and V (bf16 transposed)
#pragma unroll
  for (int it = 0; it < 16; ++it) {
    int e = it * 256 + tid;
    int tok = e >> 4;
    int d4 = (e & 15) * 4;
    int win = tok / T, tt = tok % T;
    size_t base = tok_base<WS>(gw0 + win, tt);
    uint2 kk = *(const uint2*)&qkv[base + 256 + qoff + d4];
    uint2 vv = *(const uint2*)&qkv[base + 512 + qoff + d4];
    *(uint2*)&Ks[tok * 72 + d4] = kk;
    Vt[(d4 + 0) * 264 + tok] = (u16)(vv.x & 0xffffu);
    Vt[(d4 + 1) * 264 + tok] = (u16)(vv.x >> 16);
    Vt[(d4 + 2) * 264 + tok] = (u16)(vv.y & 0xffffu);
    Vt[(d4 + 3) * 264 + tok] = (u16)(vv.y >> 16);
  }
  __syncthreads();

  const int w = tid >> 6, lane = tid & 63;
  const int fr = lane & 15, fk = lane >> 4;
  u16* prow = &Plds[(w * 16 + fr) * PL];

  for (int qi = 0; qi < 4; ++qi) {
    const int qg = w * 4 + qi;          // global q-tile 0..15
    const int win = qg / (T / 16);
    const int qt = qg % (T / 16);
    const int gw = gw0 + win;

    // Q fragments straight from global bf16
    const size_t qb = tok_base<WS>(gw, qt * 16 + fr) + qoff;
    bf16x8 qf[2];
#pragma unroll
    for (int ds = 0; ds < 2; ++ds)
      qf[ds] = *(const bf16x8*)&qkv[qb + ds * 32 + fk * 8];

    // S^T tiles
    f32x4 sv[KT];
#pragma unroll
    for (int kt = 0; kt < KT; ++kt) {
      const u16* krow = &Ks[(win * T + kt * 16 + fr) * 72];
      bf16x8 k0 = *(const bf16x8*)&krow[fk * 8];
      bf16x8 k1 = *(const bf16x8*)&krow[32 + fk * 8];
      f32x4 s = {};
      s = __builtin_amdgcn_mfma_f32_16x16x32_bf16(k0, qf[0], s, 0, 0, 0);
      s = __builtin_amdgcn_mfma_f32_16x16x32_bf16(k1, qf[1], s, 0, 0, 0);
      sv[kt] = s;
    }

    // softmax for query fr (keys spread over kt,r and the 4 fk-groups)
    float rmax = -3e38f;
#pragma unroll
    for (int kt = 0; kt < KT; ++kt)
#pragma unroll
      for (int r = 0; r < 4; ++r) rmax = fmaxf(rmax, sv[kt][r]);
    rmax = fmaxf(rmax, __shfl_xor(rmax, 16));
    rmax = fmaxf(rmax, __shfl_xor(rmax, 32));
    const float m = rmax * 0.125f;
    float l = 0.f;
#pragma unroll
    for (int kt = 0; kt < KT; ++kt)
#pragma unroll
      for (int r = 0; r < 4; ++r) {
        float ev = __expf(sv[kt][r] * 0.125f - m);
        sv[kt][r] = ev;
        l += ev;
      }
    l += __shfl_xor(l, 16);
    l += __shfl_xor(l, 32);
    const float linv = 1.f / l;

    // P -> LDS [query][key] bf16 (keys fk*4..fk*4+3 contiguous per kt)
#pragma unroll
    for (int kt = 0; kt < KT; ++kt) {
      uint2 pp;
      pp.x = pk2(sv[kt][0], sv[kt][1]);
      pp.y = pk2(sv[kt][2], sv[kt][3]);
      *(uint2*)&prow[kt * 16 + fk * 4] = pp;
    }
    __asm__ __volatile__("s_waitcnt lgkmcnt(0)" ::: "memory");
    __builtin_amdgcn_sched_barrier(0);

    // O = P . V
    f32x4 ov[4] = {};
#pragma unroll
    for (int ks = 0; ks < KS; ++ks) {
      bf16x8 pf = *(const bf16x8*)&prow[ks * 32 + fk * 8];
#pragma unroll
      for (int dt = 0; dt < 4; ++dt) {
        bf16x8 vf = *(const bf16x8*)&Vt[(dt * 16 + fr) * 264 + win * T + ks * 32 + fk * 8];
        ov[dt] = __builtin_amdgcn_mfma_f32_16x16x32_bf16(pf, vf, ov[dt], 0, 0, 0);
      }
    }

    // scale by 1/l (routed from fr-space to fk*4+r-space) and store bf16
#pragma unroll
    for (int r = 0; r < 4; ++r) {
      float lr = __shfl(linv, fk * 4 + r);
      size_t ob = tok_base<WS>(gw, qt * 16 + fk * 4 + r) + qoff;
#pragma unroll
      for (int dt = 0; dt < 4; ++dt)
        qkv[ob + dt * 16 + fr] = f2b(ov[dt][r] * lr);
    }
  }
}

// ---------------- Kernel 3: proj GEMM — counted-vmcnt dbuf pipeline ------
// A = qkv[:,0:256] bf16 (row stride 768), B = wp [256][256] bf16.
// Epilogue: + bias + residual, fp32 out in [c][sp] layout (coalesced float4).
__global__ __launch_bounds__(256) void gemm_proj(const u16* __restrict__ qkv,
                                                 const u16* __restrict__ wp,
                                                 const float* __restrict__ bias,
                                                 const float* __restrict__ x,
                                                 float* __restrict__ out) {
  __shared__ u16 As[2][128 * 64];
  __shared__ u16 Bs[2][128 * 64];
  const int tid = threadIdx.x;
  const int bid = blockIdx.x;
  const int logical = (bid & 7) * 256 + (bid >> 3);
  const int m0 = (logical >> 1) * 128;
  const int n0 = (logical & 1) * 128;
  const int lane = tid & 63, w = tid >> 6;
  const int wr = w >> 1, wc = w & 1;
  const int fr = lane & 15, fk = lane >> 4;
  const int frx = (fr & 7) << 3;
  const int kcs = ((tid & 7) * 8) ^ (((tid >> 3) & 7) << 3);
  const int srow = tid >> 3;
  const int b = m0 >> 14;
  f32x4 acc[4][4] = {};

#define STAGE_PRJ(B, KT)                                                     \
  do {                                                                       \
    const int k0s = (KT)*64;                                                 \
    _Pragma("unroll") for (int it = 0; it < 4; ++it) {                       \
      int row = it * 32 + srow;                                              \
      u16* la = &As[B][(it * 256 + (tid & 192)) * 8];                        \
      u16* lb = &Bs[B][(it * 256 + (tid & 192)) * 8];                        \
      gload_lds16(&qkv[(size_t)(m0 + row) * 768 + k0s + kcs], la);           \
      gload_lds16(&wp[((size_t)(n0 + row) << 8) + k0s + kcs], lb);           \
    }                                                                        \
  } while (0)

#define COMP_PRJ(B)                                                          \
  do {                                                                       \
    _Pragma("unroll") for (int kk = 0; kk < 2; ++kk) {                       \
      const int kb = (kk * 32 + fk * 8) ^ frx;                               \
      bf16x8 af[4], bfr[4];                                                  \
      _Pragma("unroll") for (int i = 0; i < 4; ++i) {                        \
        af[i] = *(const bf16x8*)&As[B][(wr * 64 + i * 16 + fr) * 64 + kb];   \
        bfr[i] = *(const bf16x8*)&Bs[B][(wc * 64 + i * 16 + fr) * 64 + kb];  \
      }                                                                      \
      _Pragma("unroll") for (int i = 0; i < 4; ++i)                          \
          _Pragma("unroll") for (int j = 0; j < 4; ++j) acc[i][j] =          \
          __builtin_amdgcn_mfma_f32_16x16x32_bf16(af[i], bfr[j],             \
                                                  acc[i][j], 0, 0, 0);       \
    }                                                                        \
  } while (0)

#define PHASE(WAITN)                                                         \
  asm volatile("s_waitcnt vmcnt(" #WAITN ")" ::: "memory");                  \
  __builtin_amdgcn_s_barrier();                                              \
  __builtin_amdgcn_sched_barrier(0)

#define PHASE_END()                                                          \
  __builtin_amdgcn_sched_barrier(0);                                         \
  __builtin_amdgcn_s_barrier()

  STAGE_PRJ(0, 0);
  STAGE_PRJ(1, 1);
  PHASE(8);
  COMP_PRJ(0);
  PHASE_END();
  STAGE_PRJ(0, 2);
  PHASE(8);
  COMP_PRJ(1);
  PHASE_END();
  STAGE_PRJ(1, 3);
  PHASE(8);
  COMP_PRJ(0);
  PHASE_END();
  PHASE(0);
  COMP_PRJ(1);
#undef STAGE_PRJ
#undef COMP_PRJ
#undef PHASE
#undef PHASE_END

  // acc[i][j][r]: m = m0+wr*64+i*16+fk*4+r, n = n0+wc*64+j*16+fr
#pragma unroll
  for (int i = 0; i < 4; ++i) {
    const int sp = (m0 & 16383) + wr * 64 + i * 16 + fk * 4;
#pragma unroll
    for (int j = 0; j < 4; ++j) {
      const int n = n0 + wc * 64 + j * 16 + fr;
      const size_t o = ((size_t)(b * 256 + n) << 14) + sp;
      const float4 r4 = *(const float4*)&x[o];
      const float bb = bias[n];
      float4 v = make_float4(acc[i][j][0] + bb + r4.x, acc[i][j][1] + bb + r4.y,
                             acc[i][j][2] + bb + r4.z, acc[i][j][3] + bb + r4.w);
      *(float4*)&out[o] = v;
    }
  }
}

extern "C" void kernel_launch(void* const* d_in, const int* in_sizes, int n_in,
                              void* d_out, int out_size, void* d_ws, size_t ws_size,
                              hipStream_t stream) {
  const float* x = (const float*)d_in[0];
  const float* qkv_w = (const float*)d_in[1];
  const float* proj_w = (const float*)d_in[2];
  const float* proj_b = (const float*)d_in[3];
  float* out = (float*)d_out;
  // workspace layout (bf16):
  //   qkv : 131072*768 u16 = 192 MiB
  //   wq  : 768*256 u16, wp : 256*256 u16
  u16* qkv = (u16*)d_ws;
  u16* wq = qkv + (size_t)131072 * 768;
  u16* wp = wq + (size_t)768 * 256;

  wprep<<<16, 256, 0, stream>>>(qkv_w, proj_w, wq, wp);
  gemm_qkv<<<6144, 256, 0, stream>>>(x, wq, qkv);
  win_small<<<1024, 256, 0, stream>>>(qkv);           // heads 0 (ws2) + 1 (ws4)
  win_attn_mfma<8><<<512, 256, 0, stream>>>(qkv, 2);
  win_attn_mfma<16><<<512, 256, 0, stream>>>(qkv, 3);
  gemm_proj<<<2048, 256, 0, stream>>>(qkv, wp, proj_b, x, out);
}

// Round 8
// 309.934 us; speedup vs baseline: 1.1401x; 1.1365x over previous
//
#include <hip/hip_runtime.h>
#include <hip/hip_bf16.h>
#include <cstddef>
#include <cstdint>

typedef unsigned short u16;
typedef unsigned int uint32;
typedef __attribute__((ext_vector_type(8))) short bf16x8;
typedef __attribute__((ext_vector_type(4))) float f32x4;

#define SPATIAL 16384
#define TOTAL_M 131072

__device__ __forceinline__ u16 f2b(float f) {
  __hip_bfloat16 h = __float2bfloat16(f);
  return *reinterpret_cast<u16*>(&h);
}
__device__ __forceinline__ uint32 pk2(float a, float b) {
  return (uint32)f2b(a) | ((uint32)f2b(b) << 16);
}
__device__ __forceinline__ float blo(uint32 u) {
  union { uint32 u; float f; } c; c.u = u << 16; return c.f;
}
__device__ __forceinline__ float bhi(uint32 u) {
  union { uint32 u; float f; } c; c.u = u & 0xffff0000u; return c.f;
}

// async global->LDS, 16B per lane; lds base must be wave-uniform
__device__ __forceinline__ void gload_lds16(const u16* g, u16* l) {
  __builtin_amdgcn_global_load_lds(
      (const __attribute__((address_space(1))) void*)g,
      (__attribute__((address_space(3))) void*)l, 16, 0, 0);
}

// token base (element index into [131072][768]) for window gw, in-window token tt
template <int WS>
__device__ __forceinline__ size_t tok_base(int gw, int tt) {
  constexpr int WG = 128 / WS;
  constexpr int NWIN = WG * WG;
  int bb = gw / NWIN, rr = gw % NWIN;
  int gy = rr / WG, gx = rr % WG;
  int yy = gy * WS + tt / WS, xx = gx * WS + tt % WS;
  return (((size_t)bb * 128 + yy) * 128 + xx) * 768;
}

// ---------------- Kernel 0: prep -----------------------------------------
// blocks 0..2047: transpose+convert x [b][k][sp] fp32 -> xT [m][k] bf16
// blocks 2048..2063: convert qkv_w / proj_w fp32 -> bf16
__global__ __launch_bounds__(256) void prep(const float* __restrict__ x,
                                            const float* __restrict__ qw,
                                            const float* __restrict__ pw,
                                            u16* __restrict__ xT,
                                            u16* __restrict__ wq,
                                            u16* __restrict__ wp) {
  const int tid = threadIdx.x;
  const int bid = blockIdx.x;
  if (bid >= 2048) {
    const int t = (bid - 2048) * 256 + tid;
#pragma unroll
    for (int i = 0; i < 16; ++i) {
      const int e = i * 4096 + t;  // float4 index, 65536 total
      if (e < 49152) {
        float4 v = *(const float4*)&qw[(size_t)e * 4];
        ushort4 o;
        o.x = f2b(v.x); o.y = f2b(v.y); o.z = f2b(v.z); o.w = f2b(v.w);
        *(ushort4*)&wq[(size_t)e * 4] = o;
      } else {
        float4 v = *(const float4*)&pw[(size_t)(e - 49152) * 4];
        ushort4 o;
        o.x = f2b(v.x); o.y = f2b(v.y); o.z = f2b(v.z); o.w = f2b(v.w);
        *(ushort4*)&wp[(size_t)(e - 49152) * 4] = o;
      }
    }
    return;
  }
  __shared__ u16 Ts[64 * 256];
  const int b = bid >> 8;
  const int sp0 = (bid & 255) * 64;
#pragma unroll
  for (int it = 0; it < 16; ++it) {
    int e = it * 256 + tid;
    int k = e >> 4;
    int c4 = (e & 15) * 4;
    float4 v = *(const float4*)&x[(((size_t)(b * 256 + k)) << 14) + sp0 + c4];
    Ts[(c4 + 0) * 256 + (k ^ ((((c4 + 0)) & 31) << 3))] = f2b(v.x);
    Ts[(c4 + 1) * 256 + (k ^ ((((c4 + 1)) & 31) << 3))] = f2b(v.y);
    Ts[(c4 + 2) * 256 + (k ^ ((((c4 + 2)) & 31) << 3))] = f2b(v.z);
    Ts[(c4 + 3) * 256 + (k ^ ((((c4 + 3)) & 31) << 3))] = f2b(v.w);
  }
  __syncthreads();
#pragma unroll
  for (int it = 0; it < 8; ++it) {
    int e = it * 256 + tid;
    int sp = e >> 5;
    int kc = (e & 31) * 8;
    bf16x8 row = *(const bf16x8*)&Ts[sp * 256 + (kc ^ ((sp & 31) << 3))];
    *(bf16x8*)&xT[((size_t)(b * 16384 + sp0 + sp)) * 256 + kc] = row;
  }
}

// ---------------- Kernel 1: qkv GEMM — R2 serial m97 structure (best) ----
// A = xT [131072][256] bf16, B = wq [768][256] bf16, C = qkv bf16.
// global_load_lds dwordx4 staging; LDS linear, source pre-swizzled,
// ds_read_b128 with same XOR. Serial stage->compute, 32KB LDS, 4 blk/CU.
__global__ __launch_bounds__(256) void gemm_qkv(const u16* __restrict__ xT,
                                                const u16* __restrict__ wq,
                                                u16* __restrict__ qkv) {
  __shared__ u16 As[128 * 64];
  __shared__ u16 Bs[128 * 64];
  const int tid = threadIdx.x;
  const int n0 = blockIdx.x * 128;
  const int m0 = blockIdx.y * 128;
  const int lane = tid & 63, w = tid >> 6;
  const int wr = w >> 1, wc = w & 1;
  const int fr = lane & 15, fk = lane >> 4;
  const int frx = (fr & 7) << 3;
  f32x4 acc[4][4] = {};
  for (int kt = 0; kt < 4; ++kt) {
    const int k0 = kt * 64;
#pragma unroll
    for (int it = 0; it < 4; ++it) {
      int e = it * 256 + tid;
      int row = e >> 3;
      int kcs = ((e & 7) * 8) ^ ((row & 7) << 3);
      u16* la = &As[(it * 256 + (tid & 192)) * 8];
      u16* lb = &Bs[(it * 256 + (tid & 192)) * 8];
      gload_lds16(&xT[((size_t)(m0 + row) << 8) + k0 + kcs], la);
      gload_lds16(&wq[((size_t)(n0 + row) << 8) + k0 + kcs], lb);
    }
    __syncthreads();
#pragma unroll
    for (int kk = 0; kk < 2; ++kk) {
      const int kb = (kk * 32 + fk * 8) ^ frx;
      bf16x8 af[4], bfr[4];
#pragma unroll
      for (int i = 0; i < 4; ++i) {
        af[i] = *(const bf16x8*)&As[(wr * 64 + i * 16 + fr) * 64 + kb];
        bfr[i] = *(const bf16x8*)&Bs[(wc * 64 + i * 16 + fr) * 64 + kb];
      }
#pragma unroll
      for (int i = 0; i < 4; ++i)
#pragma unroll
        for (int j = 0; j < 4; ++j)
          acc[i][j] = __builtin_amdgcn_mfma_f32_16x16x32_bf16(bfr[j], af[i], acc[i][j], 0, 0, 0);
    }
    __syncthreads();
  }
  // acc[i][j][r] = C[m = m0+wr*64+i*16+fr][n = n0+wc*64+j*16+fk*4+r]
#pragma unroll
  for (int i = 0; i < 4; ++i) {
    const size_t row = (size_t)(m0 + wr * 64 + i * 16 + fr) * 768;
#pragma unroll
    for (int j = 0; j < 4; ++j) {
      uint2 p;
      p.x = pk2(acc[i][j][0], acc[i][j][1]);
      p.y = pk2(acc[i][j][2], acc[i][j][3]);
      *(uint2*)&qkv[row + n0 + wc * 64 + j * 16 + fk * 4] = p;
    }
  }
}

// ---------------- Kernel 2a: small-window attention body (fp32 VALU) -----
template <int WS>
__device__ __forceinline__ void win_attn_body(u16* __restrict__ qkv, int head,
                                              int bid, u16 (*Ks)[68], u16 (*Vs)[68]) {
  constexpr int T = WS * WS;
  constexpr int G = 256 / T;
  const int tid = threadIdx.x;
  const int gw0 = bid * G;
  const int qoff = head * 64;

#pragma unroll
  for (int i = 0; i < 16; ++i) {
    int e4 = i * 256 + tid;
    int tok = e4 >> 4;
    int d4 = (e4 & 15) * 4;
    size_t base = tok_base<WS>(gw0 + tok / T, tok % T);
    *(uint2*)&Ks[tok][d4] = *(const uint2*)&qkv[base + 256 + qoff + d4];
    *(uint2*)&Vs[tok][d4] = *(const uint2*)&qkv[base + 512 + qoff + d4];
  }
  __syncthreads();

  const int myw = tid / T;
  const int mytt = tid % T;
  const size_t mybase = tok_base<WS>(gw0 + myw, mytt);

  float q[64];
#pragma unroll
  for (int d4 = 0; d4 < 16; ++d4) {
    uint2 q2 = *(const uint2*)&qkv[mybase + qoff + d4 * 4];
    q[d4 * 4 + 0] = blo(q2.x); q[d4 * 4 + 1] = bhi(q2.x);
    q[d4 * 4 + 2] = blo(q2.y); q[d4 * 4 + 3] = bhi(q2.y);
  }
  const int rbase = myw * T;

  float mmax = -1e30f, lsum = 0.f;
  for (int j = 0; j < T; ++j) {
    float s = 0.f;
#pragma unroll
    for (int d4 = 0; d4 < 16; ++d4) {
      uint2 k2 = *(const uint2*)&Ks[rbase + j][d4 * 4];
      s = fmaf(q[d4 * 4 + 0], blo(k2.x), s);
      s = fmaf(q[d4 * 4 + 1], bhi(k2.x), s);
      s = fmaf(q[d4 * 4 + 2], blo(k2.y), s);
      s = fmaf(q[d4 * 4 + 3], bhi(k2.y), s);
    }
    s *= 0.125f;
    const float mn = fmaxf(mmax, s);
    lsum = lsum * __expf(mmax - mn) + __expf(s - mn);
    mmax = mn;
  }
  const float inv = 1.f / lsum;

  float acc[64] = {};
  for (int j = 0; j < T; ++j) {
    float s = 0.f;
#pragma unroll
    for (int d4 = 0; d4 < 16; ++d4) {
      uint2 k2 = *(const uint2*)&Ks[rbase + j][d4 * 4];
      s = fmaf(q[d4 * 4 + 0], blo(k2.x), s);
      s = fmaf(q[d4 * 4 + 1], bhi(k2.x), s);
      s = fmaf(q[d4 * 4 + 2], blo(k2.y), s);
      s = fmaf(q[d4 * 4 + 3], bhi(k2.y), s);
    }
    const float p = __expf(s * 0.125f - mmax) * inv;
#pragma unroll
    for (int d4 = 0; d4 < 16; ++d4) {
      uint2 v2 = *(const uint2*)&Vs[rbase + j][d4 * 4];
      acc[d4 * 4 + 0] = fmaf(p, blo(v2.x), acc[d4 * 4 + 0]);
      acc[d4 * 4 + 1] = fmaf(p, bhi(v2.x), acc[d4 * 4 + 1]);
      acc[d4 * 4 + 2] = fmaf(p, blo(v2.y), acc[d4 * 4 + 2]);
      acc[d4 * 4 + 3] = fmaf(p, bhi(v2.y), acc[d4 * 4 + 3]);
    }
  }
#pragma unroll
  for (int d4 = 0; d4 < 16; ++d4) {
    uint2 o2;
    o2.x = pk2(acc[d4 * 4 + 0], acc[d4 * 4 + 1]);
    o2.y = pk2(acc[d4 * 4 + 2], acc[d4 * 4 + 3]);
    *(uint2*)&qkv[mybase + qoff + d4 * 4] = o2;
  }
}

// merged heads 0 (ws=2) and 1 (ws=4): one launch, latency overlaps
__global__ __launch_bounds__(256) void win_small(u16* __restrict__ qkv) {
  __shared__ u16 Ks[256][68];
  __shared__ u16 Vs[256][68];
  if (blockIdx.x < 512)
    win_attn_body<2>(qkv, 0, blockIdx.x, Ks, Vs);
  else
    win_attn_body<4>(qkv, 1, blockIdx.x - 512, Ks, Vs);
}

// ---------------- Kernel 2b: MFMA windowed attention (ws=8/16) ----------
// NW = waves per block. ws8: NW=4 (identical to prior). ws16: NW=8
// (512 threads, 2 qtiles/wave) -> 2 waves/SIMD instead of 1 at the same
// 1 block/CU (LDS 138KB) — doubles latency hiding for the worst kernel.
template <int WS, int NW>
__global__ __launch_bounds__(NW * 64) void win_attn_mfma(u16* __restrict__ qkv, int head) {
  constexpr int T = WS * WS;          // 64 or 256
  constexpr int G = 256 / T;          // windows per block
  constexpr int KT = T / 16;          // 16-key tiles per window
  constexpr int KS = T / 32;          // PV K=32 steps
  constexpr int PL = T + 8;           // padded P row (u16)
  constexpr int NT = NW * 64;         // threads
  constexpr int QPW = (G * T / 16) / NW;  // qtiles per wave
  __shared__ u16 Ks[256 * 72];        // [block token][d], pad 72
  __shared__ u16 Vt[64 * 264];        // [d][block token], pad 264
  __shared__ u16 Plds[NW * 16 * PL];  // per-wave [query16][key T]
  const int tid = threadIdx.x;
  const int gw0 = blockIdx.x * G;
  const int qoff = head * 64;

  // stage K (bf16 rows, straight copy) and V (bf16 transposed)
#pragma unroll
  for (int it = 0; it < 4096 / NT; ++it) {
    int e = it * NT + tid;
    int tok = e >> 4;
    int d4 = (e & 15) * 4;
    int win = tok / T, tt = tok % T;
    size_t base = tok_base<WS>(gw0 + win, tt);
    uint2 kk = *(const uint2*)&qkv[base + 256 + qoff + d4];
    uint2 vv = *(const uint2*)&qkv[base + 512 + qoff + d4];
    *(uint2*)&Ks[tok * 72 + d4] = kk;
    Vt[(d4 + 0) * 264 + tok] = (u16)(vv.x & 0xffffu);
    Vt[(d4 + 1) * 264 + tok] = (u16)(vv.x >> 16);
    Vt[(d4 + 2) * 264 + tok] = (u16)(vv.y & 0xffffu);
    Vt[(d4 + 3) * 264 + tok] = (u16)(vv.y >> 16);
  }
  __syncthreads();

  const int w = tid >> 6, lane = tid & 63;
  const int fr = lane & 15, fk = lane >> 4;
  u16* prow = &Plds[(w * 16 + fr) * PL];

  for (int qi = 0; qi < QPW; ++qi) {
    const int qg = w * QPW + qi;        // global q-tile
    const int win = qg / (T / 16);
    const int qt = qg % (T / 16);
    const int gw = gw0 + win;

    // Q fragments straight from global bf16
    const size_t qb = tok_base<WS>(gw, qt * 16 + fr) + qoff;
    bf16x8 qf[2];
#pragma unroll
    for (int ds = 0; ds < 2; ++ds)
      qf[ds] = *(const bf16x8*)&qkv[qb + ds * 32 + fk * 8];

    // S^T tiles
    f32x4 sv[KT];
#pragma unroll
    for (int kt = 0; kt < KT; ++kt) {
      const u16* krow = &Ks[(win * T + kt * 16 + fr) * 72];
      bf16x8 k0 = *(const bf16x8*)&krow[fk * 8];
      bf16x8 k1 = *(const bf16x8*)&krow[32 + fk * 8];
      f32x4 s = {};
      s = __builtin_amdgcn_mfma_f32_16x16x32_bf16(k0, qf[0], s, 0, 0, 0);
      s = __builtin_amdgcn_mfma_f32_16x16x32_bf16(k1, qf[1], s, 0, 0, 0);
      sv[kt] = s;
    }

    // softmax for query fr (keys spread over kt,r and the 4 fk-groups)
    float rmax = -3e38f;
#pragma unroll
    for (int kt = 0; kt < KT; ++kt)
#pragma unroll
      for (int r = 0; r < 4; ++r) rmax = fmaxf(rmax, sv[kt][r]);
    rmax = fmaxf(rmax, __shfl_xor(rmax, 16));
    rmax = fmaxf(rmax, __shfl_xor(rmax, 32));
    const float m = rmax * 0.125f;
    float l = 0.f;
#pragma unroll
    for (int kt = 0; kt < KT; ++kt)
#pragma unroll
      for (int r = 0; r < 4; ++r) {
        float ev = __expf(sv[kt][r] * 0.125f - m);
        sv[kt][r] = ev;
        l += ev;
      }
    l += __shfl_xor(l, 16);
    l += __shfl_xor(l, 32);
    const float linv = 1.f / l;

    // P -> LDS [query][key] bf16 (keys fk*4..fk*4+3 contiguous per kt)
#pragma unroll
    for (int kt = 0; kt < KT; ++kt) {
      uint2 pp;
      pp.x = pk2(sv[kt][0], sv[kt][1]);
      pp.y = pk2(sv[kt][2], sv[kt][3]);
      *(uint2*)&prow[kt * 16 + fk * 4] = pp;
    }
    __asm__ __volatile__("s_waitcnt lgkmcnt(0)" ::: "memory");
    __builtin_amdgcn_sched_barrier(0);

    // O = P . V
    f32x4 ov[4] = {};
#pragma unroll
    for (int ks = 0; ks < KS; ++ks) {
      bf16x8 pf = *(const bf16x8*)&prow[ks * 32 + fk * 8];
#pragma unroll
      for (int dt = 0; dt < 4; ++dt) {
        bf16x8 vf = *(const bf16x8*)&Vt[(dt * 16 + fr) * 264 + win * T + ks * 32 + fk * 8];
        ov[dt] = __builtin_amdgcn_mfma_f32_16x16x32_bf16(pf, vf, ov[dt], 0, 0, 0);
      }
    }

    // scale by 1/l (routed from fr-space to fk*4+r-space) and store bf16
#pragma unroll
    for (int r = 0; r < 4; ++r) {
      float lr = __shfl(linv, fk * 4 + r);
      size_t ob = tok_base<WS>(gw, qt * 16 + fk * 4 + r) + qoff;
#pragma unroll
      for (int dt = 0; dt < 4; ++dt)
        qkv[ob + dt * 16 + fr] = f2b(ov[dt][r] * lr);
    }
  }
}

// ---------------- Kernel 3: proj GEMM — counted-vmcnt dbuf pipeline ------
// A = qkv[:,0:256] bf16 (row stride 768), B = wp [256][256] bf16.
// Epilogue: + bias + residual, fp32 out in [c][sp] layout (coalesced float4).
__global__ __launch_bounds__(256) void gemm_proj(const u16* __restrict__ qkv,
                                                 const u16* __restrict__ wp,
                                                 const float* __restrict__ bias,
                                                 const float* __restrict__ x,
                                                 float* __restrict__ out) {
  __shared__ u16 As[2][128 * 64];
  __shared__ u16 Bs[2][128 * 64];
  const int tid = threadIdx.x;
  const int bid = blockIdx.x;
  const int logical = (bid & 7) * 256 + (bid >> 3);
  const int m0 = (logical >> 1) * 128;
  const int n0 = (logical & 1) * 128;
  const int lane = tid & 63, w = tid >> 6;
  const int wr = w >> 1, wc = w & 1;
  const int fr = lane & 15, fk = lane >> 4;
  const int frx = (fr & 7) << 3;
  const int kcs = ((tid & 7) * 8) ^ (((tid >> 3) & 7) << 3);
  const int srow = tid >> 3;
  const int b = m0 >> 14;
  f32x4 acc[4][4] = {};

#define STAGE_PRJ(B, KT)                                                     \
  do {                                                                       \
    const int k0s = (KT)*64;                                                 \
    _Pragma("unroll") for (int it = 0; it < 4; ++it) {                       \
      int row = it * 32 + srow;                                              \
      u16* la = &As[B][(it * 256 + (tid & 192)) * 8];                        \
      u16* lb = &Bs[B][(it * 256 + (tid & 192)) * 8];                        \
      gload_lds16(&qkv[(size_t)(m0 + row) * 768 + k0s + kcs], la);           \
      gload_lds16(&wp[((size_t)(n0 + row) << 8) + k0s + kcs], lb);           \
    }                                                                        \
  } while (0)

#define COMP_PRJ(B)                                                          \
  do {                                                                       \
    _Pragma("unroll") for (int kk = 0; kk < 2; ++kk) {                       \
      const int kb = (kk * 32 + fk * 8) ^ frx;                               \
      bf16x8 af[4], bfr[4];                                                  \
      _Pragma("unroll") for (int i = 0; i < 4; ++i) {                        \
        af[i] = *(const bf16x8*)&As[B][(wr * 64 + i * 16 + fr) * 64 + kb];   \
        bfr[i] = *(const bf16x8*)&Bs[B][(wc * 64 + i * 16 + fr) * 64 + kb];  \
      }                                                                      \
      _Pragma("unroll") for (int i = 0; i < 4; ++i)                          \
          _Pragma("unroll") for (int j = 0; j < 4; ++j) acc[i][j] =          \
          __builtin_amdgcn_mfma_f32_16x16x32_bf16(af[i], bfr[j],             \
                                                  acc[i][j], 0, 0, 0);       \
    }                                                                        \
  } while (0)

#define PHASE(WAITN)                                                         \
  asm volatile("s_waitcnt vmcnt(" #WAITN ")" ::: "memory");                  \
  __builtin_amdgcn_s_barrier();                                              \
  __builtin_amdgcn_sched_barrier(0)

#define PHASE_END()                                                          \
  __builtin_amdgcn_sched_barrier(0);                                         \
  __builtin_amdgcn_s_barrier()

  STAGE_PRJ(0, 0);
  STAGE_PRJ(1, 1);
  PHASE(8);
  COMP_PRJ(0);
  PHASE_END();
  STAGE_PRJ(0, 2);
  PHASE(8);
  COMP_PRJ(1);
  PHASE_END();
  STAGE_PRJ(1, 3);
  PHASE(8);
  COMP_PRJ(0);
  PHASE_END();
  PHASE(0);
  COMP_PRJ(1);
#undef STAGE_PRJ
#undef COMP_PRJ
#undef PHASE
#undef PHASE_END

  // acc[i][j][r]: m = m0+wr*64+i*16+fk*4+r, n = n0+wc*64+j*16+fr
#pragma unroll
  for (int i = 0; i < 4; ++i) {
    const int sp = (m0 & 16383) + wr * 64 + i * 16 + fk * 4;
#pragma unroll
    for (int j = 0; j < 4; ++j) {
      const int n = n0 + wc * 64 + j * 16 + fr;
      const size_t o = ((size_t)(b * 256 + n) << 14) + sp;
      const float4 r4 = *(const float4*)&x[o];
      const float bb = bias[n];
      float4 v = make_float4(acc[i][j][0] + bb + r4.x, acc[i][j][1] + bb + r4.y,
                             acc[i][j][2] + bb + r4.z, acc[i][j][3] + bb + r4.w);
      *(float4*)&out[o] = v;
    }
  }
}

extern "C" void kernel_launch(void* const* d_in, const int* in_sizes, int n_in,
                              void* d_out, int out_size, void* d_ws, size_t ws_size,
                              hipStream_t stream) {
  const float* x = (const float*)d_in[0];
  const float* qkv_w = (const float*)d_in[1];
  const float* proj_w = (const float*)d_in[2];
  const float* proj_b = (const float*)d_in[3];
  float* out = (float*)d_out;
  // workspace layout (bf16):
  //   qkv : 131072*768 u16 = 192 MiB
  //   xT  : 131072*256 u16 =  64 MiB
  //   wq  : 768*256 u16, wp : 256*256 u16
  u16* qkv = (u16*)d_ws;
  u16* xT = qkv + (size_t)131072 * 768;
  u16* wq = xT + (size_t)131072 * 256;
  u16* wp = wq + (size_t)768 * 256;

  prep<<<2064, 256, 0, stream>>>(x, qkv_w, proj_w, xT, wq, wp);
  gemm_qkv<<<dim3(6, 1024), 256, 0, stream>>>(xT, wq, qkv);
  win_small<<<1024, 256, 0, stream>>>(qkv);              // heads 0 (ws2) + 1 (ws4)
  win_attn_mfma<8, 4><<<512, 256, 0, stream>>>(qkv, 2);
  win_attn_mfma<16, 8><<<512, 512, 0, stream>>>(qkv, 3); // 8 waves, 2 waves/SIMD
  gemm_proj<<<2048, 256, 0, stream>>>(qkv, wp, proj_b, x, out);
}